// Round 4
// baseline (2838.195 us; speedup 1.0000x reference)
//
#include <hip/hip_runtime.h>
#include <math.h>

// MySimpleRNN on MI355X — weight-stationary-in-VGPR fp16 hi/lo MFMA.
// h = tanh(x_t@wx + b + h@wh), 64 steps, B=4096, NF=128, NH=512.
//
// Round-3 post-mortem: cross-block exchange pays L2 writeback+invalidate each
// step (WRITE_SIZE 18->674 MB, 600 GB/s HBM) — abandoned. Round-2 floor was
// the per-CU weight stream (1.25 MB/step through the L1 port, 8.5 us/step).
// This round removes that stream entirely: the CU register file is 2 MB
// (4 SIMD x 2048 VGPR x 64 lanes x 4 B), so the full hi/lo weight set
// (1.25 MB) lives in VGPRs. 16 waves x 32-col slice = 320 VGPR/thread of
// weights (WH 256 + WX 64), loaded once before the t-loop. launch_bounds
// (1024,4) gives a 512-reg budget; ~390 used -> no spill (m08: ok to 450).
// h and x are kept in MFMA-A-fragment-linear LDS (lane-linear 16B/lane ->
// contiguous, conflict-free ds_read_b128; validated in round 3's own-half
// path). Per-step floor is now the MFMA pipe (~3.9 us/step).
// Numerics: identical product set + accumulation order as round 2.
//
// mfma_f32_16x16x32_f16 layouts (verified learn_hip m89/m91/m120):
//   A: lane holds A[m=lane&15][k=(lane>>4)*8+j], j=0..7
//   B: lane holds B[k=(lane>>4)*8+j][n=lane&15]
//   C/D: reg r holds C[row=(lane>>4)*4+r][col=lane&15]

#define T_STEPS 64
#define NFD     128
#define NHD     512
#define THREADS 1024         // 16 waves, 4 per SIMD

typedef _Float16 half8 __attribute__((ext_vector_type(8)));
typedef _Float16 half2v __attribute__((ext_vector_type(2)));
typedef float float4v __attribute__((ext_vector_type(4)));

// ---- prep: split wh/wx into fp16 hi/lo, pack B-fragment-linear (round-2 layout, proven) ----
// whp: fi = ((w8*16 + kb)*4 + nt4)*64 + l ; element j of half8 fi <-
//      wh[(kb*32 + (l>>4)*8 + j)*512 + w8*64 + nt4*16 + (l&15)]
// wxp: fi = ((w8*4  + kb)*4 + nt4)*64 + l ; same with wx, kb 0..3
__global__ __launch_bounds__(256) void rnn_prep(
    const float* __restrict__ wh, const float* __restrict__ wx,
    _Float16* __restrict__ whp_hi, _Float16* __restrict__ whp_lo,
    _Float16* __restrict__ wxp_hi, _Float16* __restrict__ wxp_lo)
{
    int idx = blockIdx.x * 256 + threadIdx.x;   // 0..262143
    {
        int j  = idx & 7;
        int l  = (idx >> 3) & 63;
        int nt = (idx >> 9) & 3;
        int kb = (idx >> 11) & 15;
        int w  = idx >> 15;                     // 0..7
        int k  = kb * 32 + (l >> 4) * 8 + j;
        int n  = w * 64 + nt * 16 + (l & 15);
        float v = wh[k * NHD + n];
        _Float16 hi = (_Float16)v;
        whp_hi[idx] = hi;
        whp_lo[idx] = (_Float16)(v - (float)hi);
    }
    if (idx < 65536) {
        int j  = idx & 7;
        int l  = (idx >> 3) & 63;
        int nt = (idx >> 9) & 3;
        int kb = (idx >> 11) & 3;
        int w  = idx >> 13;                     // 0..7
        int k  = kb * 32 + (l >> 4) * 8 + j;
        int n  = w * 64 + nt * 16 + (l & 15);
        float v = wx[k * NHD + n];
        _Float16 hi = (_Float16)v;
        wxp_hi[idx] = hi;
        wxp_lo[idx] = (_Float16)(v - (float)hi);
    }
}

// branch-free tanh: clamp +-9, (e-1)/(e+1), e = 2^(2x*log2e)
__device__ __forceinline__ float fast_tanh(float v) {
    float xc = fminf(fmaxf(v, -9.0f), 9.0f);
    float e  = __builtin_amdgcn_exp2f(xc * 2.8853900817779268f);
    return (e - 1.0f) * __builtin_amdgcn_rcpf(e + 1.0f);
}

// ---- main fused recurrence: weights resident in VGPRs ----
__global__ __launch_bounds__(THREADS, 4) void rnn_mfma(
    const float* __restrict__ x,
    const float* __restrict__ bias,
    const _Float16* __restrict__ whp_hi, const _Float16* __restrict__ whp_lo,
    const _Float16* __restrict__ wxp_hi, const _Float16* __restrict__ wxp_lo,
    float* __restrict__ out)
{
    // fragment-linear LDS: [kb][lane][j] halfs, 16B/lane contiguous per kb.
    __shared__ _Float16 s_fh[16 * 64 * 8];   // h hi, 16 KB
    __shared__ _Float16 s_fl[16 * 64 * 8];   // h lo, 16 KB
    __shared__ _Float16 s_xh[4 * 64 * 8];    // x hi,  4 KB
    __shared__ _Float16 s_xl[4 * 64 * 8];    // x lo,  4 KB  -> 40 KB total

    const int tid  = (int)threadIdx.x;
    const int lane = tid & 63;
    const int w    = tid >> 6;        // wave 0..15, owns cols [w*32, w*32+32)
    const int m    = lane & 15;       // A-row / C-col lane index
    const int quad = lane >> 4;
    const int row0 = (int)blockIdx.x * 16;

    // zero h fragments (h(0) = 0)
    for (int i = tid; i < 16 * 64 * 8; i += THREADS) {
        s_fh[i] = (_Float16)0.f;
        s_fl[i] = (_Float16)0.f;
    }

    // bias for this lane's 2 col-tiles
    float bv[2];
    #pragma unroll
    for (int nt = 0; nt < 2; ++nt) bv[nt] = bias[w * 32 + nt * 16 + m];

    // ---- preload the wave's weight slice into registers (once) ----
    // round-2 pointer math: 32-col slice of the 64-col packing group
    const half8* wxh = (const half8*)wxp_hi + (size_t)(w >> 1) * 1024 + (w & 1) * 128;
    const half8* wxl = (const half8*)wxp_lo + (size_t)(w >> 1) * 1024 + (w & 1) * 128;
    const half8* whh = (const half8*)whp_hi + (size_t)(w >> 1) * 4096 + (w & 1) * 128;
    const half8* whl = (const half8*)whp_lo + (size_t)(w >> 1) * 4096 + (w & 1) * 128;

    half8 WHh[16][2], WHl[16][2];   // 256 VGPRs
    half8 WXh[4][2],  WXl[4][2];    //  64 VGPRs
    #pragma unroll
    for (int kb = 0; kb < 16; ++kb) {
        #pragma unroll
        for (int nt = 0; nt < 2; ++nt) {
            WHh[kb][nt] = whh[kb * 256 + nt * 64 + lane];
            WHl[kb][nt] = whl[kb * 256 + nt * 64 + lane];
        }
    }
    #pragma unroll
    for (int kb = 0; kb < 4; ++kb) {
        #pragma unroll
        for (int nt = 0; nt < 2; ++nt) {
            WXh[kb][nt] = wxh[kb * 256 + nt * 64 + lane];
            WXl[kb][nt] = wxl[kb * 256 + nt * 64 + lane];
        }
    }

    // x prefetch: 1024 threads cover 16 rows x 128 floats, 2 floats each.
    // Staged directly in A-fragment coords: value x[row][col] lives at
    // (kb*64 + (row + 16*((col&31)>>3)))*8 + (col&7), kb = col>>5.
    const int xrow  = tid >> 6;          // 0..15
    const int xcol  = (tid & 63) * 2;    // 0..126 (even -> j even, half2-aligned)
    const int xkb   = xcol >> 5;
    const int xkk   = xcol & 31;
    const int xoff  = (xkb * 64 + (xrow + 16 * (xkk >> 3))) * 8 + (xkk & 7);
    const float* xptr = x + (size_t)(row0 + xrow) * (T_STEPS * NFD) + xcol;
    float2 px = *(const float2*)xptr;

    // epilogue fragment coords: value (row=quad*4+r, col=w*32+nt*16+m) ->
    // kb = w, lane' = quad*4+r + 16*(nt*2 + (m>>3)), j = m&7.
    const int eBase = w * 64 * 8 + (m & 7);
    const int eQ    = quad * 4;
    const int eHiM  = 16 * (m >> 3);

    for (int t = 0; t < T_STEPS; ++t) {
        // (a) stage x(t): fp32 -> hi/lo fp16, fragment-linear
        {
            half2v vh, vl;
            float xs[2] = {px.x, px.y};
            #pragma unroll
            for (int j = 0; j < 2; ++j) {
                _Float16 hi = (_Float16)xs[j];
                vh[j] = hi;
                vl[j] = (_Float16)(xs[j] - (float)hi);
            }
            *(half2v*)&s_xh[xoff] = vh;
            *(half2v*)&s_xl[xoff] = vl;
        }
        __syncthreads();   // (1) x staged + h(t-1) frag writes visible

        if (t + 1 < T_STEPS) px = *(const float2*)(xptr + (t + 1) * NFD);

        float4v acc[2];
        #pragma unroll
        for (int nt = 0; nt < 2; ++nt) {
            acc[nt][0] = bv[nt]; acc[nt][1] = bv[nt];
            acc[nt][2] = bv[nt]; acc[nt][3] = bv[nt];
        }

        // (b) input projection: K = 128 -> 4 k-blocks (weights in regs)
        #pragma unroll
        for (int kb = 0; kb < 4; ++kb) {
            half8 ah = *(const half8*)&s_xh[(kb * 64 + lane) * 8];
            half8 al = *(const half8*)&s_xl[(kb * 64 + lane) * 8];
            acc[0] = __builtin_amdgcn_mfma_f32_16x16x32_f16(ah, WXh[kb][0], acc[0], 0, 0, 0);
            acc[0] = __builtin_amdgcn_mfma_f32_16x16x32_f16(al, WXh[kb][0], acc[0], 0, 0, 0);
            acc[0] = __builtin_amdgcn_mfma_f32_16x16x32_f16(ah, WXl[kb][0], acc[0], 0, 0, 0);
            acc[1] = __builtin_amdgcn_mfma_f32_16x16x32_f16(ah, WXh[kb][1], acc[1], 0, 0, 0);
            acc[1] = __builtin_amdgcn_mfma_f32_16x16x32_f16(al, WXh[kb][1], acc[1], 0, 0, 0);
            acc[1] = __builtin_amdgcn_mfma_f32_16x16x32_f16(ah, WXl[kb][1], acc[1], 0, 0, 0);
        }

        // (c) recurrence: K = 512 -> 16 k-blocks (weights in regs)
        #pragma unroll
        for (int kb = 0; kb < 16; ++kb) {
            half8 ah = *(const half8*)&s_fh[(kb * 64 + lane) * 8];
            half8 al = *(const half8*)&s_fl[(kb * 64 + lane) * 8];
            acc[0] = __builtin_amdgcn_mfma_f32_16x16x32_f16(ah, WHh[kb][0], acc[0], 0, 0, 0);
            acc[0] = __builtin_amdgcn_mfma_f32_16x16x32_f16(al, WHh[kb][0], acc[0], 0, 0, 0);
            acc[0] = __builtin_amdgcn_mfma_f32_16x16x32_f16(ah, WHl[kb][0], acc[0], 0, 0, 0);
            acc[1] = __builtin_amdgcn_mfma_f32_16x16x32_f16(ah, WHh[kb][1], acc[1], 0, 0, 0);
            acc[1] = __builtin_amdgcn_mfma_f32_16x16x32_f16(al, WHh[kb][1], acc[1], 0, 0, 0);
            acc[1] = __builtin_amdgcn_mfma_f32_16x16x32_f16(ah, WHl[kb][1], acc[1], 0, 0, 0);
        }

        __syncthreads();   // (2) all h/x fragment reads for step t done

        // (d) epilogue: tanh, split, write h(t) fragments (or final output)
        if (t == T_STEPS - 1) {
            #pragma unroll
            for (int nt = 0; nt < 2; ++nt)
                #pragma unroll
                for (int r = 0; r < 4; ++r)
                    out[(size_t)(row0 + quad * 4 + r) * NHD + w * 32 + nt * 16 + m] =
                        fast_tanh(acc[nt][r]);
        } else {
            #pragma unroll
            for (int nt = 0; nt < 2; ++nt) {
                #pragma unroll
                for (int r = 0; r < 4; ++r) {
                    float v = fast_tanh(acc[nt][r]);
                    _Float16 hi = (_Float16)v;
                    int fo = eBase + (eQ + r + 16 * (nt * 2) + eHiM) * 8;
                    s_fh[fo] = hi;
                    s_fl[fo] = (_Float16)(v - (float)hi);
                }
            }
        }
    }
}

extern "C" void kernel_launch(void* const* d_in, const int* in_sizes, int n_in,
                              void* d_out, int out_size, void* d_ws, size_t ws_size,
                              hipStream_t stream) {
    const float* x    = (const float*)d_in[0];  // [B, 64, 128]
    const float* wx   = (const float*)d_in[1];  // [128, 512]
    const float* wh   = (const float*)d_in[2];  // [512, 512]
    const float* bias = (const float*)d_in[3];  // [512]
    float* out = (float*)d_out;                 // [B, 512]

    // workspace (fp16): whp_hi 512KB | whp_lo 512KB | wxp_hi 128KB | wxp_lo 128KB
    char* ws = (char*)d_ws;
    _Float16* whp_hi = (_Float16*)(ws);
    _Float16* whp_lo = (_Float16*)(ws + 524288);
    _Float16* wxp_hi = (_Float16*)(ws + 1048576);
    _Float16* wxp_lo = (_Float16*)(ws + 1048576 + 131072);

    rnn_prep<<<1024, 256, 0, stream>>>(wh, wx, whp_hi, whp_lo, wxp_hi, wxp_lo);

    const int B = in_sizes[0] / (T_STEPS * NFD);   // 4096
    rnn_mfma<<<B / 16, THREADS, 0, stream>>>(x, bias, whp_hi, whp_lo, wxp_hi, wxp_lo, out);
}

// Round 5
// 2797.893 us; speedup vs baseline: 1.0144x; 1.0144x over previous
//
#include <hip/hip_runtime.h>
#include <math.h>

// MySimpleRNN on MI355X — hybrid-resident weights (VGPR-pinned + LDS) fp16 hi/lo MFMA.
// h = tanh(x_t@wx + b + h@wh), 64 steps, B=4096, NF=128, NH=512.
//
// R4 post-mortem: register file is 512 KB/CU (not 2 MB); 1024-thr block forces
// a 128-VGPR cap, so 320 weight VGPRs spilled to scratch (WRITE 315 MB spill
// stores, FETCH 7.8 GB spill reloads). Full weight residency is impossible.
// This round: PARTIAL residency on the proven round-2 streaming structure.
//  - 10 wh_hi frags/thread pinned in VGPRs via asm volatile("+v") (40 VGPR;
//    total ~104 < 128 cap -> no spill, cannot be rematerialized).
//  - 7 wh_hi frags/wave resident in LDS (112 KB; staged once).
//  - h/x kept in MFMA-A-fragment-linear LDS (R4 layout, proven correct;
//    conflict-free lane-linear ds_read_b128).
//  - remaining 63 frags/wave (wh_hi tail, all wh_lo, all wx) streamed from L2
//    per step exactly as round 2.
// Stream: 1.25 MB -> ~1.0 MB/step/CU; floor 8.5 -> ~6.8 us/step.
//
// mfma_f32_16x16x32_f16 layouts (verified learn_hip m89/m91/m120):
//   A: lane holds A[m=lane&15][k=(lane>>4)*8+j], j=0..7
//   B: lane holds B[k=(lane>>4)*8+j][n=lane&15]
//   C/D: reg r holds C[row=(lane>>4)*4+r][col=lane&15]

#define T_STEPS 64
#define NFD     128
#define NHD     512
#define THREADS 1024         // 16 waves, 4 per SIMD (structural 128-VGPR cap)

typedef _Float16 half8 __attribute__((ext_vector_type(8)));
typedef _Float16 half2v __attribute__((ext_vector_type(2)));
typedef float float4v __attribute__((ext_vector_type(4)));

// ---- prep: split wh/wx into fp16 hi/lo, pack B-fragment-linear (round-2 layout, proven) ----
// whp: fi = ((w8*16 + kb)*4 + nt4)*64 + l ; element j of half8 fi <-
//      wh[(kb*32 + (l>>4)*8 + j)*512 + w8*64 + nt4*16 + (l&15)]
// wxp: fi = ((w8*4  + kb)*4 + nt4)*64 + l ; same with wx, kb 0..3
__global__ __launch_bounds__(256) void rnn_prep(
    const float* __restrict__ wh, const float* __restrict__ wx,
    _Float16* __restrict__ whp_hi, _Float16* __restrict__ whp_lo,
    _Float16* __restrict__ wxp_hi, _Float16* __restrict__ wxp_lo)
{
    int idx = blockIdx.x * 256 + threadIdx.x;   // 0..262143
    {
        int j  = idx & 7;
        int l  = (idx >> 3) & 63;
        int nt = (idx >> 9) & 3;
        int kb = (idx >> 11) & 15;
        int w  = idx >> 15;                     // 0..7
        int k  = kb * 32 + (l >> 4) * 8 + j;
        int n  = w * 64 + nt * 16 + (l & 15);
        float v = wh[k * NHD + n];
        _Float16 hi = (_Float16)v;
        whp_hi[idx] = hi;
        whp_lo[idx] = (_Float16)(v - (float)hi);
    }
    if (idx < 65536) {
        int j  = idx & 7;
        int l  = (idx >> 3) & 63;
        int nt = (idx >> 9) & 3;
        int kb = (idx >> 11) & 3;
        int w  = idx >> 13;                     // 0..7
        int k  = kb * 32 + (l >> 4) * 8 + j;
        int n  = w * 64 + nt * 16 + (l & 15);
        float v = wx[k * NHD + n];
        _Float16 hi = (_Float16)v;
        wxp_hi[idx] = hi;
        wxp_lo[idx] = (_Float16)(v - (float)hi);
    }
}

// branch-free tanh: clamp +-9, (e-1)/(e+1), e = 2^(2x*log2e)
__device__ __forceinline__ float fast_tanh(float v) {
    float xc = fminf(fmaxf(v, -9.0f), 9.0f);
    float e  = __builtin_amdgcn_exp2f(xc * 2.8853900817779268f);
    return (e - 1.0f) * __builtin_amdgcn_rcpf(e + 1.0f);
}

// ---- main fused recurrence ----
__global__ __launch_bounds__(THREADS, 4) void rnn_mfma(
    const float* __restrict__ x,
    const float* __restrict__ bias,
    const _Float16* __restrict__ whp_hi, const _Float16* __restrict__ whp_lo,
    const _Float16* __restrict__ wxp_hi, const _Float16* __restrict__ wxp_lo,
    float* __restrict__ out)
{
    // fragment-linear LDS: [kb][lane][j] halfs, 16B/lane contiguous per kb.
    __shared__ _Float16 s_fh[16 * 64 * 8];     // h hi, 16 KB
    __shared__ _Float16 s_fl[16 * 64 * 8];     // h lo, 16 KB
    __shared__ _Float16 s_xh[4 * 64 * 8];      // x hi,  4 KB
    __shared__ _Float16 s_xl[4 * 64 * 8];      // x lo,  4 KB
    // LDS-resident wh_hi frags: [wave][f(7)][lane][8] -> 112 KB (total 152 KB)
    __shared__ _Float16 s_w[16 * 7 * 64 * 8];

    const int tid  = (int)threadIdx.x;
    const int lane = tid & 63;
    const int w    = tid >> 6;        // wave 0..15, owns cols [w*32, w*32+32)
    const int m    = lane & 15;
    const int quad = lane >> 4;
    const int row0 = (int)blockIdx.x * 16;

    // zero h fragments (h(0) = 0)
    for (int i = tid; i < 16 * 64 * 8; i += THREADS) {
        s_fh[i] = (_Float16)0.f;
        s_fl[i] = (_Float16)0.f;
    }

    // bias for this lane's 2 col-tiles
    float bv[2];
    #pragma unroll
    for (int nt = 0; nt < 2; ++nt) bv[nt] = bias[w * 32 + nt * 16 + m];

    // weight fragment base pointers (round-2 math: 32-col slice of 64-col group)
    const half8* wxh = (const half8*)wxp_hi + (size_t)(w >> 1) * 1024 + (w & 1) * 128;
    const half8* wxl = (const half8*)wxp_lo + (size_t)(w >> 1) * 1024 + (w & 1) * 128;
    const half8* whh = (const half8*)whp_hi + (size_t)(w >> 1) * 4096 + (w & 1) * 128;
    const half8* whl = (const half8*)whp_lo + (size_t)(w >> 1) * 4096 + (w & 1) * 128;

    // ---- VGPR-pinned resident frags: wh_hi kb 0..4, nt 0..1 (10 frags, 40 VGPR) ----
    half8 RW[10];
    #pragma unroll
    for (int i = 0; i < 10; ++i)
        RW[i] = whh[(i >> 1) * 256 + (i & 1) * 64 + lane];
    #pragma unroll
    for (int i = 0; i < 10; ++i)
        asm volatile("" : "+v"(RW[i]));   // opaque: no remat, must stay live

    // ---- LDS-resident frags: wh_hi kb 5,6,7 (nt 0,1) + kb 8 (nt 0) -> 7/wave ----
    #pragma unroll
    for (int f = 0; f < 7; ++f) {
        int kb = (f < 6) ? (5 + (f >> 1)) : 8;
        int nt = (f < 6) ? (f & 1) : 0;
        half8 v = whh[kb * 256 + nt * 64 + lane];
        *(half8*)&s_w[((w * 7 + f) * 64 + lane) * 8] = v;
    }

    // x prefetch: 1024 threads cover 16 rows x 128 floats, 2 floats each,
    // staged directly in A-fragment coords (R4 layout, proven).
    const int xrow  = tid >> 6;          // 0..15
    const int xcol  = (tid & 63) * 2;    // 0..126
    const int xkb   = xcol >> 5;
    const int xkk   = xcol & 31;
    const int xoff  = (xkb * 64 + (xrow + 16 * (xkk >> 3))) * 8 + (xkk & 7);
    const float* xptr = x + (size_t)(row0 + xrow) * (T_STEPS * NFD) + xcol;
    float2 px = *(const float2*)xptr;

    // epilogue fragment coords (R4, proven)
    const int eBase = w * 64 * 8 + (m & 7);
    const int eQ    = quad * 4;
    const int eHiM  = 16 * (m >> 3);

    for (int t = 0; t < T_STEPS; ++t) {
        // (a) stage x(t): fp32 -> hi/lo fp16, fragment-linear
        {
            half2v vh, vl;
            float xs[2] = {px.x, px.y};
            #pragma unroll
            for (int j = 0; j < 2; ++j) {
                _Float16 hi = (_Float16)xs[j];
                vh[j] = hi;
                vl[j] = (_Float16)(xs[j] - (float)hi);
            }
            *(half2v*)&s_xh[xoff] = vh;
            *(half2v*)&s_xl[xoff] = vl;
        }
        __syncthreads();   // (1) x staged + h(t-1) frags + (t=0: s_w/zero) visible

        if (t + 1 < T_STEPS) px = *(const float2*)(xptr + (t + 1) * NFD);

        float4v acc[2];
        #pragma unroll
        for (int nt = 0; nt < 2; ++nt) {
            acc[nt][0] = bv[nt]; acc[nt][1] = bv[nt];
            acc[nt][2] = bv[nt]; acc[nt][3] = bv[nt];
        }

        // (b) input projection: K = 128 -> 4 k-blocks (streamed)
        #pragma unroll
        for (int kb = 0; kb < 4; ++kb) {
            half8 ah = *(const half8*)&s_xh[(kb * 64 + lane) * 8];
            half8 al = *(const half8*)&s_xl[(kb * 64 + lane) * 8];
            half8 bh0 = wxh[kb * 256 + lane];
            half8 bh1 = wxh[kb * 256 + 64 + lane];
            half8 bl0 = wxl[kb * 256 + lane];
            half8 bl1 = wxl[kb * 256 + 64 + lane];
            acc[0] = __builtin_amdgcn_mfma_f32_16x16x32_f16(ah, bh0, acc[0], 0, 0, 0);
            acc[0] = __builtin_amdgcn_mfma_f32_16x16x32_f16(al, bh0, acc[0], 0, 0, 0);
            acc[0] = __builtin_amdgcn_mfma_f32_16x16x32_f16(ah, bl0, acc[0], 0, 0, 0);
            acc[1] = __builtin_amdgcn_mfma_f32_16x16x32_f16(ah, bh1, acc[1], 0, 0, 0);
            acc[1] = __builtin_amdgcn_mfma_f32_16x16x32_f16(al, bh1, acc[1], 0, 0, 0);
            acc[1] = __builtin_amdgcn_mfma_f32_16x16x32_f16(ah, bl1, acc[1], 0, 0, 0);
        }

        // (c) recurrence: K = 512 -> 16 k-blocks; bh from regs/LDS/global
        #pragma unroll
        for (int kb = 0; kb < 16; ++kb) {
            half8 ah = *(const half8*)&s_fh[(kb * 64 + lane) * 8];
            half8 al = *(const half8*)&s_fl[(kb * 64 + lane) * 8];
            half8 bh0, bh1;
            if (kb < 5) {
                bh0 = RW[kb * 2];
                bh1 = RW[kb * 2 + 1];
            } else if (kb < 8) {
                bh0 = *(const half8*)&s_w[((w * 7 + (kb - 5) * 2    ) * 64 + lane) * 8];
                bh1 = *(const half8*)&s_w[((w * 7 + (kb - 5) * 2 + 1) * 64 + lane) * 8];
            } else if (kb == 8) {
                bh0 = *(const half8*)&s_w[((w * 7 + 6) * 64 + lane) * 8];
                bh1 = whh[kb * 256 + 64 + lane];
            } else {
                bh0 = whh[kb * 256 + lane];
                bh1 = whh[kb * 256 + 64 + lane];
            }
            half8 bl0 = whl[kb * 256 + lane];
            half8 bl1 = whl[kb * 256 + 64 + lane];
            acc[0] = __builtin_amdgcn_mfma_f32_16x16x32_f16(ah, bh0, acc[0], 0, 0, 0);
            acc[0] = __builtin_amdgcn_mfma_f32_16x16x32_f16(al, bh0, acc[0], 0, 0, 0);
            acc[0] = __builtin_amdgcn_mfma_f32_16x16x32_f16(ah, bl0, acc[0], 0, 0, 0);
            acc[1] = __builtin_amdgcn_mfma_f32_16x16x32_f16(ah, bh1, acc[1], 0, 0, 0);
            acc[1] = __builtin_amdgcn_mfma_f32_16x16x32_f16(al, bh1, acc[1], 0, 0, 0);
            acc[1] = __builtin_amdgcn_mfma_f32_16x16x32_f16(ah, bl1, acc[1], 0, 0, 0);
        }

        __syncthreads();   // (2) all h/x fragment reads for step t done

        // (d) epilogue: tanh, split, write h(t) fragments (or final output)
        if (t == T_STEPS - 1) {
            #pragma unroll
            for (int nt = 0; nt < 2; ++nt)
                #pragma unroll
                for (int r = 0; r < 4; ++r)
                    out[(size_t)(row0 + quad * 4 + r) * NHD + w * 32 + nt * 16 + m] =
                        fast_tanh(acc[nt][r]);
        } else {
            #pragma unroll
            for (int nt = 0; nt < 2; ++nt) {
                #pragma unroll
                for (int r = 0; r < 4; ++r) {
                    float v = fast_tanh(acc[nt][r]);
                    _Float16 hi = (_Float16)v;
                    int fo = eBase + (eQ + r + 16 * (nt * 2) + eHiM) * 8;
                    s_fh[fo] = hi;
                    s_fl[fo] = (_Float16)(v - (float)hi);
                }
            }
        }
    }
}

extern "C" void kernel_launch(void* const* d_in, const int* in_sizes, int n_in,
                              void* d_out, int out_size, void* d_ws, size_t ws_size,
                              hipStream_t stream) {
    const float* x    = (const float*)d_in[0];  // [B, 64, 128]
    const float* wx   = (const float*)d_in[1];  // [128, 512]
    const float* wh   = (const float*)d_in[2];  // [512, 512]
    const float* bias = (const float*)d_in[3];  // [512]
    float* out = (float*)d_out;                 // [B, 512]

    // workspace (fp16): whp_hi 512KB | whp_lo 512KB | wxp_hi 128KB | wxp_lo 128KB
    char* ws = (char*)d_ws;
    _Float16* whp_hi = (_Float16*)(ws);
    _Float16* whp_lo = (_Float16*)(ws + 524288);
    _Float16* wxp_hi = (_Float16*)(ws + 1048576);
    _Float16* wxp_lo = (_Float16*)(ws + 1048576 + 131072);

    rnn_prep<<<1024, 256, 0, stream>>>(wh, wx, whp_hi, whp_lo, wxp_hi, wxp_lo);

    const int B = in_sizes[0] / (T_STEPS * NFD);   // 4096
    rnn_mfma<<<B / 16, THREADS, 0, stream>>>(x, bias, whp_hi, whp_lo, wxp_hi, wxp_lo, out);
}

// Round 6
// 1017.695 us; speedup vs baseline: 2.7888x; 2.7492x over previous
//
#include <hip/hip_runtime.h>
#include <math.h>

// MySimpleRNN on MI355X — round-2 streaming structure, BR=32, frag-linear LDS.
// h = tanh(x_t@wx + b + h@wh), 64 steps, B=4096, NF=128, NH=512.
//
// R4/R5 post-mortem: VGPR weight residency is impossible (512 KB/CU regfile;
// 1024-thr block caps 128 VGPR/thread; allocator spills arrays across
// barriers even when "pinned"). Reverted to the proven round-2 streaming
// kernel (843 us, 103 GB/s/CU weight stream).
// This round's single question: is the stream ceiling the per-CU L1 port
// (~153 GB/s) or the per-XCD L2 share (4.3 TB/s / consumers)? At 256 blocks
// these coincide; at 128 blocks x 16 waves they diverge. BR=32 doubles rows
// per block (12 MFMAs per 4 streamed weight frags), halves the block count.
//  - XCD-share-limited -> ~5-7 us/step (dur 480-620 us)
//  - per-CU-port-limited -> unchanged ~12.75 us/step (null result, informative)
// h/x use R4's MFMA-A-fragment-linear LDS (proven correct, conflict-free
// lane-linear ds_read_b128). Numerics: identical product set + order as R2.
//
// mfma_f32_16x16x32_f16 layouts (verified learn_hip m89/m91/m120):
//   A: lane holds A[m=lane&15][k=(lane>>4)*8+j], j=0..7
//   B: lane holds B[k=(lane>>4)*8+j][n=lane&15]
//   C/D: reg r holds C[row=(lane>>4)*4+r][col=lane&15]

#define T_STEPS 64
#define NFD     128
#define NHD     512
#define BR      32
#define THREADS 1024         // 16 waves, 4 per SIMD

typedef _Float16 half8 __attribute__((ext_vector_type(8)));
typedef _Float16 half4v __attribute__((ext_vector_type(4)));
typedef float float4v __attribute__((ext_vector_type(4)));

// ---- prep: split wh/wx into fp16 hi/lo, pack B-fragment-linear (round-2 layout, proven) ----
// whp: fi = ((w8*16 + kb)*4 + nt4)*64 + l ; element j of half8 fi <-
//      wh[(kb*32 + (l>>4)*8 + j)*512 + w8*64 + nt4*16 + (l&15)]
// wxp: fi = ((w8*4  + kb)*4 + nt4)*64 + l ; same with wx, kb 0..3
__global__ __launch_bounds__(256) void rnn_prep(
    const float* __restrict__ wh, const float* __restrict__ wx,
    _Float16* __restrict__ whp_hi, _Float16* __restrict__ whp_lo,
    _Float16* __restrict__ wxp_hi, _Float16* __restrict__ wxp_lo)
{
    int idx = blockIdx.x * 256 + threadIdx.x;   // 0..262143
    {
        int j  = idx & 7;
        int l  = (idx >> 3) & 63;
        int nt = (idx >> 9) & 3;
        int kb = (idx >> 11) & 15;
        int w  = idx >> 15;                     // 0..7
        int k  = kb * 32 + (l >> 4) * 8 + j;
        int n  = w * 64 + nt * 16 + (l & 15);
        float v = wh[k * NHD + n];
        _Float16 hi = (_Float16)v;
        whp_hi[idx] = hi;
        whp_lo[idx] = (_Float16)(v - (float)hi);
    }
    if (idx < 65536) {
        int j  = idx & 7;
        int l  = (idx >> 3) & 63;
        int nt = (idx >> 9) & 3;
        int kb = (idx >> 11) & 3;
        int w  = idx >> 13;                     // 0..7
        int k  = kb * 32 + (l >> 4) * 8 + j;
        int n  = w * 64 + nt * 16 + (l & 15);
        float v = wx[k * NHD + n];
        _Float16 hi = (_Float16)v;
        wxp_hi[idx] = hi;
        wxp_lo[idx] = (_Float16)(v - (float)hi);
    }
}

// branch-free tanh: clamp +-9, (e-1)/(e+1), e = 2^(2x*log2e)
__device__ __forceinline__ float fast_tanh(float v) {
    float xc = fminf(fmaxf(v, -9.0f), 9.0f);
    float e  = __builtin_amdgcn_exp2f(xc * 2.8853900817779268f);
    return (e - 1.0f) * __builtin_amdgcn_rcpf(e + 1.0f);
}

// ---- main fused recurrence ----
__global__ __launch_bounds__(THREADS, 4) void rnn_mfma(
    const float* __restrict__ x,
    const float* __restrict__ bias,
    const _Float16* __restrict__ whp_hi, const _Float16* __restrict__ whp_lo,
    const _Float16* __restrict__ wxp_hi, const _Float16* __restrict__ wxp_lo,
    float* __restrict__ out)
{
    // fragment-linear LDS: [rb][kb][lane][j] halfs, 16B/lane contiguous.
    __shared__ _Float16 s_fh[2 * 16 * 64 * 8];   // h hi, 32 KB
    __shared__ _Float16 s_fl[2 * 16 * 64 * 8];   // h lo, 32 KB
    __shared__ _Float16 s_xh[2 * 4 * 64 * 8];    // x hi,  8 KB
    __shared__ _Float16 s_xl[2 * 4 * 64 * 8];    // x lo,  8 KB  -> 80 KB total

    const int tid  = (int)threadIdx.x;
    const int lane = tid & 63;
    const int w    = tid >> 6;        // wave 0..15, owns cols [w*32, w*32+32)
    const int m    = lane & 15;
    const int quad = lane >> 4;
    const int row0 = (int)blockIdx.x * BR;

    // zero h fragments (h(0) = 0)
    for (int i = tid; i < 2 * 16 * 64 * 8; i += THREADS) {
        s_fh[i] = (_Float16)0.f;
        s_fl[i] = (_Float16)0.f;
    }

    // bias for this lane's 2 col-tiles
    float bv[2];
    #pragma unroll
    for (int nt = 0; nt < 2; ++nt) bv[nt] = bias[w * 32 + nt * 16 + m];

    // weight fragment base pointers (round-2 math: 32-col slice of 64-col group)
    const half8* wxh = (const half8*)wxp_hi + (size_t)(w >> 1) * 1024 + (w & 1) * 128;
    const half8* wxl = (const half8*)wxp_lo + (size_t)(w >> 1) * 1024 + (w & 1) * 128;
    const half8* whh = (const half8*)whp_hi + (size_t)(w >> 1) * 4096 + (w & 1) * 128;
    const half8* whl = (const half8*)whp_lo + (size_t)(w >> 1) * 4096 + (w & 1) * 128;

    // x prefetch: 1024 threads cover 32 rows x 128 floats, 4 floats each,
    // staged directly in A-fragment coords.
    const int xrow = tid >> 5;           // 0..31
    const int xcol = (tid & 31) * 4;     // 0..124
    const int xrb  = xrow >> 4;
    const int xrr  = xrow & 15;
    const int xkb  = xcol >> 5;
    const int xkk  = xcol & 31;          // multiple of 4; kk>>3 uniform over the 4 floats
    const int xoff = ((xrb * 4 + xkb) * 64 + (xrr + 16 * (xkk >> 3))) * 8 + (xkk & 7);
    const float* xptr = x + (size_t)(row0 + xrow) * (T_STEPS * NFD) + xcol;
    float4v px = *(const float4v*)xptr;

    // epilogue fragment coords: h[row=rb*16+quad*4+r][col=w*32+nt*16+m] ->
    // frag (rb, kb=w, lane'=quad*4+r+16*(nt*2+(m>>3)), j=m&7)   (R4, proven)
    const int eJ   = m & 7;
    const int eQ   = quad * 4;
    const int eHiM = 16 * (m >> 3);

    for (int t = 0; t < T_STEPS; ++t) {
        // (a) stage x(t): fp32 -> hi/lo fp16, fragment-linear
        {
            half4v vh, vl;
            float xs[4] = {px[0], px[1], px[2], px[3]};
            #pragma unroll
            for (int j = 0; j < 4; ++j) {
                _Float16 hi = (_Float16)xs[j];
                vh[j] = hi;
                vl[j] = (_Float16)(xs[j] - (float)hi);
            }
            *(half4v*)&s_xh[xoff] = vh;
            *(half4v*)&s_xl[xoff] = vl;
        }
        __syncthreads();   // (1) x staged + h(t-1) frag writes visible

        if (t + 1 < T_STEPS) px = *(const float4v*)(xptr + (t + 1) * NFD);

        float4v acc[2][2];
        #pragma unroll
        for (int rb = 0; rb < 2; ++rb)
            #pragma unroll
            for (int nt = 0; nt < 2; ++nt) {
                acc[rb][nt][0] = bv[nt]; acc[rb][nt][1] = bv[nt];
                acc[rb][nt][2] = bv[nt]; acc[rb][nt][3] = bv[nt];
            }

        // (b) input projection: K = 128 -> 4 k-blocks (streamed weights)
        #pragma unroll
        for (int kb = 0; kb < 4; ++kb) {
            half8 a0h = *(const half8*)&s_xh[((    kb) * 64 + lane) * 8];
            half8 a0l = *(const half8*)&s_xl[((    kb) * 64 + lane) * 8];
            half8 a1h = *(const half8*)&s_xh[((4 + kb) * 64 + lane) * 8];
            half8 a1l = *(const half8*)&s_xl[((4 + kb) * 64 + lane) * 8];
            half8 bh0 = wxh[kb * 256 + lane];
            half8 bh1 = wxh[kb * 256 + 64 + lane];
            half8 bl0 = wxl[kb * 256 + lane];
            half8 bl1 = wxl[kb * 256 + 64 + lane];
            acc[0][0] = __builtin_amdgcn_mfma_f32_16x16x32_f16(a0h, bh0, acc[0][0], 0, 0, 0);
            acc[0][0] = __builtin_amdgcn_mfma_f32_16x16x32_f16(a0l, bh0, acc[0][0], 0, 0, 0);
            acc[0][0] = __builtin_amdgcn_mfma_f32_16x16x32_f16(a0h, bl0, acc[0][0], 0, 0, 0);
            acc[0][1] = __builtin_amdgcn_mfma_f32_16x16x32_f16(a0h, bh1, acc[0][1], 0, 0, 0);
            acc[0][1] = __builtin_amdgcn_mfma_f32_16x16x32_f16(a0l, bh1, acc[0][1], 0, 0, 0);
            acc[0][1] = __builtin_amdgcn_mfma_f32_16x16x32_f16(a0h, bl1, acc[0][1], 0, 0, 0);
            acc[1][0] = __builtin_amdgcn_mfma_f32_16x16x32_f16(a1h, bh0, acc[1][0], 0, 0, 0);
            acc[1][0] = __builtin_amdgcn_mfma_f32_16x16x32_f16(a1l, bh0, acc[1][0], 0, 0, 0);
            acc[1][0] = __builtin_amdgcn_mfma_f32_16x16x32_f16(a1h, bl0, acc[1][0], 0, 0, 0);
            acc[1][1] = __builtin_amdgcn_mfma_f32_16x16x32_f16(a1h, bh1, acc[1][1], 0, 0, 0);
            acc[1][1] = __builtin_amdgcn_mfma_f32_16x16x32_f16(a1l, bh1, acc[1][1], 0, 0, 0);
            acc[1][1] = __builtin_amdgcn_mfma_f32_16x16x32_f16(a1h, bl1, acc[1][1], 0, 0, 0);
        }

        // (c) recurrence: K = 512 -> 16 k-blocks (streamed weights)
        #pragma unroll 4
        for (int kb = 0; kb < 16; ++kb) {
            half8 a0h = *(const half8*)&s_fh[((     kb) * 64 + lane) * 8];
            half8 a0l = *(const half8*)&s_fl[((     kb) * 64 + lane) * 8];
            half8 a1h = *(const half8*)&s_fh[((16 + kb) * 64 + lane) * 8];
            half8 a1l = *(const half8*)&s_fl[((16 + kb) * 64 + lane) * 8];
            half8 bh0 = whh[kb * 256 + lane];
            half8 bh1 = whh[kb * 256 + 64 + lane];
            half8 bl0 = whl[kb * 256 + lane];
            half8 bl1 = whl[kb * 256 + 64 + lane];
            acc[0][0] = __builtin_amdgcn_mfma_f32_16x16x32_f16(a0h, bh0, acc[0][0], 0, 0, 0);
            acc[0][0] = __builtin_amdgcn_mfma_f32_16x16x32_f16(a0l, bh0, acc[0][0], 0, 0, 0);
            acc[0][0] = __builtin_amdgcn_mfma_f32_16x16x32_f16(a0h, bl0, acc[0][0], 0, 0, 0);
            acc[0][1] = __builtin_amdgcn_mfma_f32_16x16x32_f16(a0h, bh1, acc[0][1], 0, 0, 0);
            acc[0][1] = __builtin_amdgcn_mfma_f32_16x16x32_f16(a0l, bh1, acc[0][1], 0, 0, 0);
            acc[0][1] = __builtin_amdgcn_mfma_f32_16x16x32_f16(a0h, bl1, acc[0][1], 0, 0, 0);
            acc[1][0] = __builtin_amdgcn_mfma_f32_16x16x32_f16(a1h, bh0, acc[1][0], 0, 0, 0);
            acc[1][0] = __builtin_amdgcn_mfma_f32_16x16x32_f16(a1l, bh0, acc[1][0], 0, 0, 0);
            acc[1][0] = __builtin_amdgcn_mfma_f32_16x16x32_f16(a1h, bl0, acc[1][0], 0, 0, 0);
            acc[1][1] = __builtin_amdgcn_mfma_f32_16x16x32_f16(a1h, bh1, acc[1][1], 0, 0, 0);
            acc[1][1] = __builtin_amdgcn_mfma_f32_16x16x32_f16(a1l, bh1, acc[1][1], 0, 0, 0);
            acc[1][1] = __builtin_amdgcn_mfma_f32_16x16x32_f16(a1h, bl1, acc[1][1], 0, 0, 0);
        }

        __syncthreads();   // (2) all h/x fragment reads for step t done

        // (d) epilogue: tanh, split, write h(t) fragments (or final output)
        if (t == T_STEPS - 1) {
            #pragma unroll
            for (int rb = 0; rb < 2; ++rb)
                #pragma unroll
                for (int nt = 0; nt < 2; ++nt)
                    #pragma unroll
                    for (int r = 0; r < 4; ++r)
                        out[(size_t)(row0 + rb * 16 + quad * 4 + r) * NHD + w * 32 + nt * 16 + m] =
                            fast_tanh(acc[rb][nt][r]);
        } else {
            #pragma unroll
            for (int rb = 0; rb < 2; ++rb) {
                #pragma unroll
                for (int nt = 0; nt < 2; ++nt) {
                    #pragma unroll
                    for (int r = 0; r < 4; ++r) {
                        float v = fast_tanh(acc[rb][nt][r]);
                        _Float16 hi = (_Float16)v;
                        int fo = ((rb * 16 + w) * 64 + (eQ + r + 16 * (nt * 2) + eHiM)) * 8 + eJ;
                        s_fh[fo] = hi;
                        s_fl[fo] = (_Float16)(v - (float)hi);
                    }
                }
            }
        }
    }
}

extern "C" void kernel_launch(void* const* d_in, const int* in_sizes, int n_in,
                              void* d_out, int out_size, void* d_ws, size_t ws_size,
                              hipStream_t stream) {
    const float* x    = (const float*)d_in[0];  // [B, 64, 128]
    const float* wx   = (const float*)d_in[1];  // [128, 512]
    const float* wh   = (const float*)d_in[2];  // [512, 512]
    const float* bias = (const float*)d_in[3];  // [512]
    float* out = (float*)d_out;                 // [B, 512]

    // workspace (fp16): whp_hi 512KB | whp_lo 512KB | wxp_hi 128KB | wxp_lo 128KB
    char* ws = (char*)d_ws;
    _Float16* whp_hi = (_Float16*)(ws);
    _Float16* whp_lo = (_Float16*)(ws + 524288);
    _Float16* wxp_hi = (_Float16*)(ws + 1048576);
    _Float16* wxp_lo = (_Float16*)(ws + 1048576 + 131072);

    rnn_prep<<<1024, 256, 0, stream>>>(wh, wx, whp_hi, whp_lo, wxp_hi, wxp_lo);

    const int B = in_sizes[0] / (T_STEPS * NFD);   // 4096
    rnn_mfma<<<B / BR, THREADS, 0, stream>>>(x, bias, whp_hi, whp_lo, wxp_hi, wxp_lo, out);
}

// Round 7
// 795.116 us; speedup vs baseline: 3.5695x; 1.2799x over previous
//
#include <hip/hip_runtime.h>
#include <math.h>

// MySimpleRNN on MI355X — BR=16 streaming + wx LDS-resident + cross-barrier
// register prefetch. h = tanh(x_t@wx + b + h@wh), 64 steps, B=4096, NF=128, NH=512.
//
// R6 settled the ceiling question: the weight stream is PER-CU limited
// (L1/TA fill ~56-60 B/clk; BR=32 at half the blocks got slower, ruling out
// the XCD-L2-share hypothesis). R2-config runs 103 GB/s/CU = 75% of ceiling.
// This round makes the wh stream the only in-loop global traffic:
//  - wx_hi 7/8 frags per wave resident in LDS (112 KB; total 152 KB).
//  - remaining 9 wx frags prefetched into short-lived regs BEFORE the x-stage
//    barrier (completed by the barrier's vmcnt drain) -> x-proj issues zero
//    global loads; the 1.0 MB/step wh stream flows barrier-to-barrier.
//  - h/x in MFMA-A-fragment-linear LDS (R4/R5 proven; 63% fewer conflict
//    cycles than padded row-major).
// NOT a VGPR-residency attempt (R4/R5 failure): prefetch values are
// short-lived SSA temps, pressure ~100 < 128 cap.
//
// mfma_f32_16x16x32_f16 layouts (verified learn_hip m89/m91/m120):
//   A: lane holds A[m=lane&15][k=(lane>>4)*8+j], j=0..7
//   B: lane holds B[k=(lane>>4)*8+j][n=lane&15]
//   C/D: reg r holds C[row=(lane>>4)*4+r][col=lane&15]

#define T_STEPS 64
#define NFD     128
#define NHD     512
#define BR      16
#define THREADS 1024         // 16 waves, 4 per SIMD

typedef _Float16 half8 __attribute__((ext_vector_type(8)));
typedef _Float16 half2v __attribute__((ext_vector_type(2)));
typedef float float4v __attribute__((ext_vector_type(4)));

// ---- prep: split wh/wx into fp16 hi/lo, pack B-fragment-linear (round-2 layout, proven) ----
// whp: fi = ((w8*16 + kb)*4 + nt4)*64 + l ; element j of half8 fi <-
//      wh[(kb*32 + (l>>4)*8 + j)*512 + w8*64 + nt4*16 + (l&15)]
// wxp: fi = ((w8*4  + kb)*4 + nt4)*64 + l ; same with wx, kb 0..3
__global__ __launch_bounds__(256) void rnn_prep(
    const float* __restrict__ wh, const float* __restrict__ wx,
    _Float16* __restrict__ whp_hi, _Float16* __restrict__ whp_lo,
    _Float16* __restrict__ wxp_hi, _Float16* __restrict__ wxp_lo)
{
    int idx = blockIdx.x * 256 + threadIdx.x;   // 0..262143
    {
        int j  = idx & 7;
        int l  = (idx >> 3) & 63;
        int nt = (idx >> 9) & 3;
        int kb = (idx >> 11) & 15;
        int w  = idx >> 15;                     // 0..7
        int k  = kb * 32 + (l >> 4) * 8 + j;
        int n  = w * 64 + nt * 16 + (l & 15);
        float v = wh[k * NHD + n];
        _Float16 hi = (_Float16)v;
        whp_hi[idx] = hi;
        whp_lo[idx] = (_Float16)(v - (float)hi);
    }
    if (idx < 65536) {
        int j  = idx & 7;
        int l  = (idx >> 3) & 63;
        int nt = (idx >> 9) & 3;
        int kb = (idx >> 11) & 3;
        int w  = idx >> 13;                     // 0..7
        int k  = kb * 32 + (l >> 4) * 8 + j;
        int n  = w * 64 + nt * 16 + (l & 15);
        float v = wx[k * NHD + n];
        _Float16 hi = (_Float16)v;
        wxp_hi[idx] = hi;
        wxp_lo[idx] = (_Float16)(v - (float)hi);
    }
}

// branch-free tanh: clamp +-9, (e-1)/(e+1), e = 2^(2x*log2e)
__device__ __forceinline__ float fast_tanh(float v) {
    float xc = fminf(fmaxf(v, -9.0f), 9.0f);
    float e  = __builtin_amdgcn_exp2f(xc * 2.8853900817779268f);
    return (e - 1.0f) * __builtin_amdgcn_rcpf(e + 1.0f);
}

// ---- main fused recurrence ----
__global__ __launch_bounds__(THREADS, 4) void rnn_mfma(
    const float* __restrict__ x,
    const float* __restrict__ bias,
    const _Float16* __restrict__ whp_hi, const _Float16* __restrict__ whp_lo,
    const _Float16* __restrict__ wxp_hi, const _Float16* __restrict__ wxp_lo,
    float* __restrict__ out)
{
    // fragment-linear LDS: [kb][lane][j] halfs, 16B/lane contiguous per kb.
    __shared__ _Float16 s_fh[16 * 64 * 8];     // h hi, 16 KB
    __shared__ _Float16 s_fl[16 * 64 * 8];     // h lo, 16 KB
    __shared__ _Float16 s_xh[4 * 64 * 8];      // x hi,  4 KB
    __shared__ _Float16 s_xl[4 * 64 * 8];      // x lo,  4 KB
    // LDS-resident wx_hi frags: [wave][f(7)][lane][8], f = kb*2+nt (f<7) -> 112 KB
    __shared__ _Float16 s_w[16 * 7 * 64 * 8];  // total 152 KB

    const int tid  = (int)threadIdx.x;
    const int lane = tid & 63;
    const int w    = tid >> 6;        // wave 0..15, owns cols [w*32, w*32+32)
    const int m    = lane & 15;
    const int quad = lane >> 4;
    const int row0 = (int)blockIdx.x * BR;

    // zero h fragments (h(0) = 0)
    for (int i = tid; i < 16 * 64 * 8; i += THREADS) {
        s_fh[i] = (_Float16)0.f;
        s_fl[i] = (_Float16)0.f;
    }

    // bias for this lane's 2 col-tiles
    float bv[2];
    #pragma unroll
    for (int nt = 0; nt < 2; ++nt) bv[nt] = bias[w * 32 + nt * 16 + m];

    // weight fragment base pointers (round-2 math: 32-col slice of 64-col group)
    const half8* wxh = (const half8*)wxp_hi + (size_t)(w >> 1) * 1024 + (w & 1) * 128;
    const half8* wxl = (const half8*)wxp_lo + (size_t)(w >> 1) * 1024 + (w & 1) * 128;
    const half8* whh = (const half8*)whp_hi + (size_t)(w >> 1) * 4096 + (w & 1) * 128;
    const half8* whl = (const half8*)whp_lo + (size_t)(w >> 1) * 4096 + (w & 1) * 128;

    // stage resident wx_hi frags (f = kb*2+nt, f<7) into LDS once
    #pragma unroll
    for (int f = 0; f < 7; ++f) {
        int kb = f >> 1, nt = f & 1;
        half8 v = wxh[kb * 256 + nt * 64 + lane];
        *(half8*)&s_w[((w * 7 + f) * 64 + lane) * 8] = v;
    }

    // x prefetch: 1024 threads cover 16 rows x 128 floats, 2 floats each,
    // staged directly in A-fragment coords (R4/R5, proven).
    const int xrow  = tid >> 6;          // 0..15
    const int xcol  = (tid & 63) * 2;    // 0..126
    const int xkb   = xcol >> 5;
    const int xkk   = xcol & 31;
    const int xoff  = (xkb * 64 + (xrow + 16 * (xkk >> 3))) * 8 + (xkk & 7);
    const float* xptr = x + (size_t)(row0 + xrow) * (T_STEPS * NFD) + xcol;
    float2 px = *(const float2*)xptr;

    // epilogue fragment coords (R4/R5, proven)
    const int eBase = w * 64 * 8 + (m & 7);
    const int eQ    = quad * 4;
    const int eHiM  = 16 * (m >> 3);

    for (int t = 0; t < T_STEPS; ++t) {
        // (p) cross-barrier prefetch: the 9 non-resident wx frags
        // (short-lived SSA temps; completed by the barrier's vmcnt drain)
        half8 pbh31 = wxh[3 * 256 + 64 + lane];   // wx_hi kb3 nt1 (f=7)
        half8 pbl0[4], pbl1[4];
        #pragma unroll
        for (int kb = 0; kb < 4; ++kb) {
            pbl0[kb] = wxl[kb * 256 + lane];
            pbl1[kb] = wxl[kb * 256 + 64 + lane];
        }

        // (a) stage x(t): fp32 -> hi/lo fp16, fragment-linear
        {
            half2v vh, vl;
            float xs[2] = {px.x, px.y};
            #pragma unroll
            for (int j = 0; j < 2; ++j) {
                _Float16 hi = (_Float16)xs[j];
                vh[j] = hi;
                vl[j] = (_Float16)(xs[j] - (float)hi);
            }
            *(half2v*)&s_xh[xoff] = vh;
            *(half2v*)&s_xl[xoff] = vl;
        }
        __syncthreads();   // (1) x staged + h(t-1) frags (+ t=0: s_w, zeros) visible

        if (t + 1 < T_STEPS) px = *(const float2*)(xptr + (t + 1) * NFD);

        float4v acc[2];
        #pragma unroll
        for (int nt = 0; nt < 2; ++nt) {
            acc[nt][0] = bv[nt]; acc[nt][1] = bv[nt];
            acc[nt][2] = bv[nt]; acc[nt][3] = bv[nt];
        }

        // (b) input projection: K = 128 -> 4 k-blocks; zero global loads
        #pragma unroll
        for (int kb = 0; kb < 4; ++kb) {
            half8 ah = *(const half8*)&s_xh[(kb * 64 + lane) * 8];
            half8 al = *(const half8*)&s_xl[(kb * 64 + lane) * 8];
            half8 bh0 = *(const half8*)&s_w[((w * 7 + kb * 2) * 64 + lane) * 8];
            half8 bh1 = (kb < 3)
                ? *(const half8*)&s_w[((w * 7 + kb * 2 + 1) * 64 + lane) * 8]
                : pbh31;
            half8 bl0 = pbl0[kb];
            half8 bl1 = pbl1[kb];
            acc[0] = __builtin_amdgcn_mfma_f32_16x16x32_f16(ah, bh0, acc[0], 0, 0, 0);
            acc[0] = __builtin_amdgcn_mfma_f32_16x16x32_f16(al, bh0, acc[0], 0, 0, 0);
            acc[0] = __builtin_amdgcn_mfma_f32_16x16x32_f16(ah, bl0, acc[0], 0, 0, 0);
            acc[1] = __builtin_amdgcn_mfma_f32_16x16x32_f16(ah, bh1, acc[1], 0, 0, 0);
            acc[1] = __builtin_amdgcn_mfma_f32_16x16x32_f16(al, bh1, acc[1], 0, 0, 0);
            acc[1] = __builtin_amdgcn_mfma_f32_16x16x32_f16(ah, bl1, acc[1], 0, 0, 0);
        }

        // (c) recurrence: K = 512 -> 16 k-blocks (the only in-loop global stream)
        #pragma unroll 4
        for (int kb = 0; kb < 16; ++kb) {
            half8 ah = *(const half8*)&s_fh[(kb * 64 + lane) * 8];
            half8 al = *(const half8*)&s_fl[(kb * 64 + lane) * 8];
            half8 bh0 = whh[kb * 256 + lane];
            half8 bh1 = whh[kb * 256 + 64 + lane];
            half8 bl0 = whl[kb * 256 + lane];
            half8 bl1 = whl[kb * 256 + 64 + lane];
            acc[0] = __builtin_amdgcn_mfma_f32_16x16x32_f16(ah, bh0, acc[0], 0, 0, 0);
            acc[0] = __builtin_amdgcn_mfma_f32_16x16x32_f16(al, bh0, acc[0], 0, 0, 0);
            acc[0] = __builtin_amdgcn_mfma_f32_16x16x32_f16(ah, bl0, acc[0], 0, 0, 0);
            acc[1] = __builtin_amdgcn_mfma_f32_16x16x32_f16(ah, bh1, acc[1], 0, 0, 0);
            acc[1] = __builtin_amdgcn_mfma_f32_16x16x32_f16(al, bh1, acc[1], 0, 0, 0);
            acc[1] = __builtin_amdgcn_mfma_f32_16x16x32_f16(ah, bl1, acc[1], 0, 0, 0);
        }

        __syncthreads();   // (2) all h/x fragment reads for step t done

        // (d) epilogue: tanh, split, write h(t) fragments (or final output)
        if (t == T_STEPS - 1) {
            #pragma unroll
            for (int nt = 0; nt < 2; ++nt)
                #pragma unroll
                for (int r = 0; r < 4; ++r)
                    out[(size_t)(row0 + quad * 4 + r) * NHD + w * 32 + nt * 16 + m] =
                        fast_tanh(acc[nt][r]);
        } else {
            #pragma unroll
            for (int nt = 0; nt < 2; ++nt) {
                #pragma unroll
                for (int r = 0; r < 4; ++r) {
                    float v = fast_tanh(acc[nt][r]);
                    _Float16 hi = (_Float16)v;
                    int fo = eBase + (eQ + r + 16 * (nt * 2) + eHiM) * 8;
                    s_fh[fo] = hi;
                    s_fl[fo] = (_Float16)(v - (float)hi);
                }
            }
        }
    }
}

extern "C" void kernel_launch(void* const* d_in, const int* in_sizes, int n_in,
                              void* d_out, int out_size, void* d_ws, size_t ws_size,
                              hipStream_t stream) {
    const float* x    = (const float*)d_in[0];  // [B, 64, 128]
    const float* wx   = (const float*)d_in[1];  // [128, 512]
    const float* wh   = (const float*)d_in[2];  // [512, 512]
    const float* bias = (const float*)d_in[3];  // [512]
    float* out = (float*)d_out;                 // [B, 512]

    // workspace (fp16): whp_hi 512KB | whp_lo 512KB | wxp_hi 128KB | wxp_lo 128KB
    char* ws = (char*)d_ws;
    _Float16* whp_hi = (_Float16*)(ws);
    _Float16* whp_lo = (_Float16*)(ws + 524288);
    _Float16* wxp_hi = (_Float16*)(ws + 1048576);
    _Float16* wxp_lo = (_Float16*)(ws + 1048576 + 131072);

    rnn_prep<<<1024, 256, 0, stream>>>(wh, wx, whp_hi, whp_lo, wxp_hi, wxp_lo);

    const int B = in_sizes[0] / (T_STEPS * NFD);   // 4096
    rnn_mfma<<<B / BR, THREADS, 0, stream>>>(x, bias, whp_hi, whp_lo, wxp_hi, wxp_lo, out);
}